// Round 2
// baseline (2202.739 us; speedup 1.0000x reference)
//
#include <hip/hip_runtime.h>
#include <hip/hip_bf16.h>

#define NN 9216      // W*H
#define CCH 256      // channels
#define NT 144       // m-tiles of 64

typedef unsigned short u16;
typedef unsigned int   u32;

static __device__ __forceinline__ u16 f2bf(float f){
    u32 u = __builtin_bit_cast(u32, f);
    u += 0x7fffu + ((u >> 16) & 1u);   // RNE; inputs finite
    return (u16)(u >> 16);
}
static __device__ __forceinline__ float bf2f(u16 h){
    u32 u = ((u32)h) << 16;
    return __builtin_bit_cast(float, u);
}

// ---------------- Kernel 1: q,k projection + center + sumsq partials ----------
extern "C" __global__ __launch_bounds__(256)
void qk_proj(const float* __restrict__ x, const float* __restrict__ sf,
             const float* __restrict__ Wq, const float* __restrict__ bq,
             const float* __restrict__ Wk, const float* __restrict__ bk,
             float* __restrict__ qhat, float* __restrict__ khat,
             float* __restrict__ pq, float* __restrict__ pk)
{
    const int t = threadIdx.x;
    const int n = blockIdx.x * 256 + t;
    float q[32], k[32];
    #pragma unroll
    for (int o = 0; o < 32; ++o){ q[o] = bq[o]; k[o] = bk[o]; }
    for (int c = 0; c < CCH; ++c){
        float s  = sf[c * NN + n];
        float xv = x [c * NN + n];
        #pragma unroll
        for (int o = 0; o < 32; ++o){
            q[o] = fmaf(Wq[o * CCH + c], s,  q[o]);
            k[o] = fmaf(Wk[o * CCH + c], xv, k[o]);
        }
    }
    float mq = 0.f, mk = 0.f;
    #pragma unroll
    for (int o = 0; o < 32; ++o){ mq += q[o]; mk += k[o]; }
    mq *= (1.f/32.f); mk *= (1.f/32.f);
    float sq = 0.f, sk = 0.f;
    #pragma unroll
    for (int o = 0; o < 32; ++o){
        q[o] -= mq; k[o] -= mk;
        sq = fmaf(q[o], q[o], sq);
        sk = fmaf(k[o], k[o], sk);
        qhat[o * NN + n] = q[o];
        khat[o * NN + n] = k[o];
    }
    __shared__ float red[256];
    red[t] = sq; __syncthreads();
    for (int s2 = 128; s2 > 0; s2 >>= 1){ if (t < s2) red[t] += red[t + s2]; __syncthreads(); }
    if (t == 0) pq[blockIdx.x] = red[0];
    __syncthreads();
    red[t] = sk; __syncthreads();
    for (int s2 = 128; s2 > 0; s2 >>= 1){ if (t < s2) red[t] += red[t + s2]; __syncthreads(); }
    if (t == 0) pk[blockIdx.x] = red[0];
}

// ---------------- Kernel 2: v projection, stored transposed [m][c] in bf16 ----
extern "C" __global__ __launch_bounds__(256)
void v_proj(const float* __restrict__ x, const float* __restrict__ Wv,
            const float* __restrict__ bv, u16* __restrict__ vtb)
{
    const int t  = threadIdx.x;
    const int m  = blockIdx.x * 64 + (t & 63);
    const int og = t >> 6;                 // wave id: channels og*64 .. +63
    float acc[64];
    #pragma unroll
    for (int i = 0; i < 64; ++i) acc[i] = bv[og * 64 + i];
    for (int c = 0; c < CCH; ++c){
        float xv = x[c * NN + m];
        #pragma unroll
        for (int i = 0; i < 64; ++i)
            acc[i] = fmaf(Wv[(og * 64 + i) * CCH + c], xv, acc[i]);
    }
    #pragma unroll
    for (int i = 0; i < 64; i += 8){
        u32 w0 = (u32)f2bf(acc[i+0]) | ((u32)f2bf(acc[i+1]) << 16);
        u32 w1 = (u32)f2bf(acc[i+2]) | ((u32)f2bf(acc[i+3]) << 16);
        u32 w2 = (u32)f2bf(acc[i+4]) | ((u32)f2bf(acc[i+5]) << 16);
        u32 w3 = (u32)f2bf(acc[i+6]) | ((u32)f2bf(acc[i+7]) << 16);
        uint4 pk4; pk4.x = w0; pk4.y = w1; pk4.z = w2; pk4.w = w3;
        *reinterpret_cast<uint4*>(vtb + (size_t)m * 256 + og * 64 + i) = pk4;
    }
}

// ---------------- Kernel 3: fused two-pass attention + PV + epilogue ----------
// block: 256 threads, 16 rows (n) per block; grid 576
extern "C" __global__ __launch_bounds__(256)
void attn_fused(const float* __restrict__ qhat, const float* __restrict__ khat,
                const u16* __restrict__ vtb,
                const float* __restrict__ pq, const float* __restrict__ pk,
                const float* __restrict__ x, const float* __restrict__ gammap,
                float* __restrict__ outf, float* __restrict__ attnf)
{
    __shared__ float qs[16][36];
    __shared__ float ks[64][36];
    __shared__ float ps[16][68];
    __shared__ float rs_inv[16];
    __shared__ float part[16][17];

    const int t    = threadIdx.x;
    const int lane = t & 63;
    const int g    = t >> 6;          // wave id 0..3
    const int n0   = blockIdx.x * 16;

    float sq = 0.f, sk = 0.f;
    for (int i = 0; i < 36; ++i){ sq += pq[i]; sk += pk[i]; }
    const float inv_den = rsqrtf(sq) * rsqrtf(sk);

    // load qs tile [16 rows][32 o]
    if (t < 128){
        int r = t & 15, og = t >> 4;  // og 0..7
        float4 qv;
        qv.x = qhat[(og*4+0)*NN + n0 + r];
        qv.y = qhat[(og*4+1)*NN + n0 + r];
        qv.z = qhat[(og*4+2)*NN + n0 + r];
        qv.w = qhat[(og*4+3)*NN + n0 + r];
        *reinterpret_cast<float4*>(&qs[r][og*4]) = qv;
    }

    // ---- pass 1: row sums of exp(energy) ----
    float qreg[32];
    {
        const int r = t & 15;
        #pragma unroll
        for (int o = 0; o < 32; ++o) qreg[o] = qhat[o*NN + n0 + r];
    }
    const int mg = t >> 4;   // 0..15, each handles 4 m per tile
    float partial = 0.f;
    for (int tile = 0; tile < NT; ++tile){
        const int m0 = tile * 64;
        {   // stage k tile: ks[mm][o], stride 36 keeps b128 conflict-free
            int mm = lane;
            #pragma unroll
            for (int h = 0; h < 2; ++h){
                int ob = (g + h*4) * 4;
                float4 kv;
                kv.x = khat[(ob+0)*NN + m0 + mm];
                kv.y = khat[(ob+1)*NN + m0 + mm];
                kv.z = khat[(ob+2)*NN + m0 + mm];
                kv.w = khat[(ob+3)*NN + m0 + mm];
                *reinterpret_cast<float4*>(&ks[mm][ob]) = kv;
            }
        }
        __syncthreads();
        #pragma unroll
        for (int j = 0; j < 4; ++j){
            const int mm = mg * 4 + j;
            float e = 0.f;
            #pragma unroll
            for (int o = 0; o < 32; ++o) e = fmaf(qreg[o], ks[mm][o], e);
            partial += __expf(e * inv_den);
        }
        __syncthreads();
    }
    part[mg][t & 15] = partial;
    __syncthreads();
    if (t < 16){
        float s = 0.f;
        #pragma unroll
        for (int i = 0; i < 16; ++i) s += part[i][t];
        rs_inv[t] = 1.f / s;
    }
    __syncthreads();

    // ---- pass 2: recompute energy, write attention (f32), accumulate PV ----
    float acc[4][4];
    #pragma unroll
    for (int i = 0; i < 4; ++i)
        #pragma unroll
        for (int j = 0; j < 4; ++j) acc[i][j] = 0.f;

    for (int tile = 0; tile < NT; ++tile){
        const int m0 = tile * 64;
        {   // stage k tile
            int mm = lane;
            #pragma unroll
            for (int h = 0; h < 2; ++h){
                int ob = (g + h*4) * 4;
                float4 kv;
                kv.x = khat[(ob+0)*NN + m0 + mm];
                kv.y = khat[(ob+1)*NN + m0 + mm];
                kv.z = khat[(ob+2)*NN + m0 + mm];
                kv.w = khat[(ob+3)*NN + m0 + mm];
                *reinterpret_cast<float4*>(&ks[mm][ob]) = kv;
            }
        }
        __syncthreads();
        // phase A: p = exp(e)/rowsum -> global f32 + LDS
        {
            float kreg[32];
            #pragma unroll
            for (int o4 = 0; o4 < 8; ++o4){
                float4 kv = *reinterpret_cast<const float4*>(&ks[lane][o4*4]);
                kreg[o4*4+0]=kv.x; kreg[o4*4+1]=kv.y; kreg[o4*4+2]=kv.z; kreg[o4*4+3]=kv.w;
            }
            #pragma unroll
            for (int j = 0; j < 4; ++j){
                const int r = g*4 + j;
                float e = 0.f;
                #pragma unroll
                for (int o4 = 0; o4 < 8; ++o4){
                    float4 qv = *reinterpret_cast<const float4*>(&qs[r][o4*4]);
                    e = fmaf(qv.x, kreg[o4*4+0], e);
                    e = fmaf(qv.y, kreg[o4*4+1], e);
                    e = fmaf(qv.z, kreg[o4*4+2], e);
                    e = fmaf(qv.w, kreg[o4*4+3], e);
                }
                float p = __expf(e * inv_den) * rs_inv[r];
                attnf[(size_t)(n0 + r) * NN + m0 + lane] = p;
                ps[r][lane] = p;
            }
        }
        __syncthreads();
        // phase B: out[r][c] += p[r][m] * vt[m][c]
        #define FMA4(PP, VU) \
            acc[i][0] = fmaf(PP, VU.x, acc[i][0]); \
            acc[i][1] = fmaf(PP, VU.y, acc[i][1]); \
            acc[i][2] = fmaf(PP, VU.z, acc[i][2]); \
            acc[i][3] = fmaf(PP, VU.w, acc[i][3]);
        for (int mmb = 0; mmb < 64; mmb += 4){
            float4 vv[4];
            #pragma unroll
            for (int u = 0; u < 4; ++u){
                ushort4 vu = *reinterpret_cast<const ushort4*>(vtb + (size_t)(m0+mmb+u)*256 + lane*4);
                vv[u].x = bf2f(vu.x); vv[u].y = bf2f(vu.y);
                vv[u].z = bf2f(vu.z); vv[u].w = bf2f(vu.w);
            }
            #pragma unroll
            for (int i = 0; i < 4; ++i){
                float4 pv = *reinterpret_cast<const float4*>(&ps[g*4+i][mmb]);
                FMA4(pv.x, vv[0]) FMA4(pv.y, vv[1]) FMA4(pv.z, vv[2]) FMA4(pv.w, vv[3])
            }
        }
        #undef FMA4
        __syncthreads();
    }

    // epilogue: out = gamma*acc + x (f32)
    const float gam = gammap[0];
    #pragma unroll
    for (int i = 0; i < 4; ++i){
        const int nn = n0 + g*4 + i;
        #pragma unroll
        for (int j = 0; j < 4; ++j){
            const int c = lane*4 + j;
            const size_t idx = (size_t)c * NN + nn;
            outf[idx] = fmaf(gam, acc[i][j], x[idx]);
        }
    }
}

extern "C" void kernel_launch(void* const* d_in, const int* in_sizes, int n_in,
                              void* d_out, int out_size, void* d_ws, size_t ws_size,
                              hipStream_t stream)
{
    (void)in_sizes; (void)n_in; (void)out_size; (void)ws_size;
    const float* x  = (const float*)d_in[0];
    const float* sf = (const float*)d_in[1];
    const float* Wq = (const float*)d_in[2];
    const float* bq = (const float*)d_in[3];
    const float* Wk = (const float*)d_in[4];
    const float* bk = (const float*)d_in[5];
    const float* Wv = (const float*)d_in[6];
    const float* bv = (const float*)d_in[7];
    const float* gm = (const float*)d_in[8];

    float* outf  = (float*)d_out;                       // [256][9216] f32
    float* attnf = outf + (size_t)256 * 9216;           // [9216][9216] f32

    char*  ws   = (char*)d_ws;
    float* qhat = (float*)(ws);                 // 32*9216 f32   = 1,179,648 B
    float* khat = (float*)(ws + 1179648);       // 32*9216 f32   = 1,179,648 B
    u16*   vtb  = (u16*)  (ws + 2359296);       // 9216*256 bf16 = 4,718,592 B
    float* pq   = (float*)(ws + 7077888);       // 36 f32
    float* pk   = pq + 36;                      // 36 f32

    qk_proj  <<<dim3(36),  dim3(256), 0, stream>>>(x, sf, Wq, bq, Wk, bk, qhat, khat, pq, pk);
    v_proj   <<<dim3(144), dim3(256), 0, stream>>>(x, Wv, bv, vtb);
    attn_fused<<<dim3(576), dim3(256), 0, stream>>>(qhat, khat, vtb, pq, pk, x, gm, outf, attnf);
}

// Round 3
// 391.679 us; speedup vs baseline: 5.6238x; 5.6238x over previous
//
#include <hip/hip_runtime.h>
#include <hip/hip_bf16.h>

#define NN 9216      // W*H
#define CCH 256      // channels

typedef unsigned short u16;
typedef unsigned int   u32;
typedef __attribute__((ext_vector_type(8))) short bf16x8;   // 8 bf16 = 4 VGPRs
typedef __attribute__((ext_vector_type(4))) float f32x4;

static __device__ __forceinline__ u16 f2bf(float f){
    u32 u = __builtin_bit_cast(u32, f);
    u += 0x7fffu + ((u >> 16) & 1u);   // RNE; inputs finite
    return (u16)(u >> 16);
}

// ---------------- K1: fused projections ----------------
// blocks 0..71:   q,k projection + center + sumsq partials; qhb/khb bf16 [n][32]
// blocks 72..359: v projection -> vb bf16 [c][m]
extern "C" __global__ __launch_bounds__(256)
void proj_all(const float* __restrict__ x, const float* __restrict__ sf,
              const float* __restrict__ Wq, const float* __restrict__ bq,
              const float* __restrict__ Wk, const float* __restrict__ bk,
              const float* __restrict__ Wv, const float* __restrict__ bv,
              u16* __restrict__ qhb, u16* __restrict__ khb, u16* __restrict__ vb,
              float* __restrict__ pq, float* __restrict__ pk)
{
    const int bid = blockIdx.x, t = threadIdx.x;
    if (bid < 72){
        const int isk = (t >= 128);            // waves 0,1: q ; waves 2,3: k
        const int n   = bid * 128 + (t & 127);
        const float* W  = isk ? Wk : Wq;
        const float* bb = isk ? bk : bq;
        const float* in = isk ? x  : sf;
        float a[32];
        #pragma unroll
        for (int o = 0; o < 32; ++o) a[o] = bb[o];
        for (int c = 0; c < CCH; ++c){
            float v = in[c * NN + n];
            #pragma unroll
            for (int o = 0; o < 32; ++o) a[o] = fmaf(W[o * CCH + c], v, a[o]);
        }
        float mn = 0.f;
        #pragma unroll
        for (int o = 0; o < 32; ++o) mn += a[o];
        mn *= (1.f / 32.f);
        float ss = 0.f;
        #pragma unroll
        for (int o = 0; o < 32; ++o){ a[o] -= mn; ss = fmaf(a[o], a[o], ss); }
        u16* dst = (isk ? khb : qhb) + n * 32;
        #pragma unroll
        for (int i = 0; i < 32; i += 8){
            uint4 pk4;
            pk4.x = (u32)f2bf(a[i+0]) | ((u32)f2bf(a[i+1]) << 16);
            pk4.y = (u32)f2bf(a[i+2]) | ((u32)f2bf(a[i+3]) << 16);
            pk4.z = (u32)f2bf(a[i+4]) | ((u32)f2bf(a[i+5]) << 16);
            pk4.w = (u32)f2bf(a[i+6]) | ((u32)f2bf(a[i+7]) << 16);
            *reinterpret_cast<uint4*>(dst + i) = pk4;
        }
        __shared__ float red[256];
        red[t] = ss; __syncthreads();
        for (int off = 64; off > 0; off >>= 1){
            if ((t & 127) < off) red[t] += red[t + off];
            __syncthreads();
        }
        if (t == 0)   pq[bid] = red[0];
        if (t == 128) pk[bid] = red[128];
    } else {
        const int vbid = bid - 72;             // 0..287
        const int m  = vbid * 32 + (t & 31);
        const int c0 = (t >> 5) * 32;          // 8 c-groups of 32
        float acc[32];
        #pragma unroll
        for (int i = 0; i < 32; ++i) acc[i] = bv[c0 + i];
        for (int c = 0; c < CCH; ++c){
            float xv = x[c * NN + m];
            #pragma unroll
            for (int i = 0; i < 32; ++i)
                acc[i] = fmaf(Wv[(c0 + i) * CCH + c], xv, acc[i]);
        }
        #pragma unroll
        for (int i = 0; i < 32; ++i)
            vb[(c0 + i) * NN + m] = f2bf(acc[i]);
    }
}

// ---------------- Kz: zero the out-accumulator (in d_out) + rsums ----------
extern "C" __global__ __launch_bounds__(256)
void zero_ws(float* __restrict__ outacc, float* __restrict__ rsums)
{
    const int bid = blockIdx.x, t = threadIdx.x;
    float4 z = {0.f, 0.f, 0.f, 0.f};
    if (bid < 2304){
        *reinterpret_cast<float4*>(outacc + (size_t)bid * 1024 + t * 4) = z;
    } else {
        *reinterpret_cast<float4*>(rsums + (size_t)(bid - 2304) * 1024 + t * 4) = z;
    }
}

// ---------------- K2: row sums of exp(energy) via MFMA ----------------
// grid 1152: nc = bid>>3 (64 rows), ms = bid&7 (1152 cols)
extern "C" __global__ __launch_bounds__(256)
void rowsums_k(const u16* __restrict__ qhb, const u16* __restrict__ khb,
               const float* __restrict__ pq, const float* __restrict__ pk,
               float* __restrict__ rsums)
{
    const int bid = blockIdx.x;
    const int nc = bid >> 3, ms = bid & 7;
    const int t = threadIdx.x, w = t >> 6, l = t & 63, h = l >> 4, r = l & 15;
    const int n0 = nc * 64, mbase = ms * 1152;

    float sq = 0.f, sk = 0.f;
    for (int i = 0; i < 72; ++i){ sq += pq[i]; sk += pk[i]; }
    const float inv_den = rsqrtf(sq) * rsqrtf(sk);

    bf16x8 qf[4];
    #pragma unroll
    for (int nt = 0; nt < 4; ++nt)
        qf[nt] = *reinterpret_cast<const bf16x8*>(qhb + (n0 + nt*16 + r)*32 + 8*h);

    float racc[4][4];
    #pragma unroll
    for (int nt = 0; nt < 4; ++nt)
        #pragma unroll
        for (int g2 = 0; g2 < 4; ++g2) racc[nt][g2] = 0.f;

    for (int i = 0; i < 18; ++i){
        const int mcol = mbase + (w + 4*i) * 16;
        bf16x8 kf = *reinterpret_cast<const bf16x8*>(khb + (mcol + r)*32 + 8*h);
        #pragma unroll
        for (int nt = 0; nt < 4; ++nt){
            f32x4 z = {0.f,0.f,0.f,0.f};
            f32x4 e = __builtin_amdgcn_mfma_f32_16x16x32_bf16(qf[nt], kf, z, 0, 0, 0);
            #pragma unroll
            for (int g2 = 0; g2 < 4; ++g2)
                racc[nt][g2] += __expf(e[g2] * inv_den);
        }
    }
    // reduce over the 16 column-lanes (l&15)
    #pragma unroll
    for (int mask = 1; mask <= 8; mask <<= 1)
        #pragma unroll
        for (int nt = 0; nt < 4; ++nt)
            #pragma unroll
            for (int g2 = 0; g2 < 4; ++g2)
                racc[nt][g2] += __shfl_xor(racc[nt][g2], mask);

    if (r == 0){
        #pragma unroll
        for (int nt = 0; nt < 4; ++nt)
            #pragma unroll
            for (int g2 = 0; g2 < 4; ++g2)
                atomicAdd(rsums + n0 + nt*16 + 4*h + g2, racc[nt][g2]);
    }
}

// ---------------- K3: attention write + PV, all MFMA ----------------
// grid 1152: nc = bid>>3 (64 n-rows), ms = bid&7 (1152 m-cols); 18 m-tiles of 64
extern "C" __global__ __launch_bounds__(256)
void attn_main(const u16* __restrict__ qhb, const u16* __restrict__ khb,
               const u16* __restrict__ vb,
               const float* __restrict__ pq, const float* __restrict__ pk,
               const float* __restrict__ rsums,
               float* __restrict__ outacc, float* __restrict__ attnf)
{
    __shared__ u16 ps[64 * 72];   // P tile [64 n][72-padded m], 144B rows
    const int bid = blockIdx.x;
    const int nc = bid >> 3, ms = bid & 7;
    const int t = threadIdx.x, w = t >> 6, l = t & 63, h = l >> 4, r = l & 15;
    const int n0 = nc * 64, mbase = ms * 1152;

    float sq = 0.f, sk = 0.f;
    for (int i = 0; i < 72; ++i){ sq += pq[i]; sk += pk[i]; }
    const float inv_den = rsqrtf(sq) * rsqrtf(sk);

    bf16x8 qf[4];
    #pragma unroll
    for (int nt = 0; nt < 4; ++nt)
        qf[nt] = *reinterpret_cast<const bf16x8*>(qhb + (n0 + nt*16 + r)*32 + 8*h);

    float rinv[4][4];
    #pragma unroll
    for (int nt = 0; nt < 4; ++nt)
        #pragma unroll
        for (int g2 = 0; g2 < 4; ++g2)
            rinv[nt][g2] = 1.f / rsums[n0 + nt*16 + 4*h + g2];

    f32x4 acc[4][4];
    #pragma unroll
    for (int ct = 0; ct < 4; ++ct)
        #pragma unroll
        for (int nt = 0; nt < 4; ++nt)
            acc[ct][nt] = (f32x4){0.f,0.f,0.f,0.f};

    for (int mt = 0; mt < 18; ++mt){
        const int m0 = mbase + mt * 64;
        const int mcol = m0 + w * 16;
        bf16x8 kf = *reinterpret_cast<const bf16x8*>(khb + (mcol + r)*32 + 8*h);
        float p4[4][4];
        #pragma unroll
        for (int nt = 0; nt < 4; ++nt){
            f32x4 z = {0.f,0.f,0.f,0.f};
            f32x4 e = __builtin_amdgcn_mfma_f32_16x16x32_bf16(qf[nt], kf, z, 0, 0, 0);
            #pragma unroll
            for (int g2 = 0; g2 < 4; ++g2)
                p4[nt][g2] = __expf(e[g2] * inv_den) * rinv[nt][g2];
        }
        #pragma unroll
        for (int nt = 0; nt < 4; ++nt)
            #pragma unroll
            for (int g2 = 0; g2 < 4; ++g2)
                attnf[(size_t)(n0 + nt*16 + 4*h + g2) * NN + mcol + r] = p4[nt][g2];
        #pragma unroll
        for (int nt = 0; nt < 4; ++nt)
            #pragma unroll
            for (int g2 = 0; g2 < 4; ++g2)
                ps[(nt*16 + 4*h + g2) * 72 + w*16 + r] = f2bf(p4[nt][g2]);
        __syncthreads();
        // PV: D[c][n] += vb[c][m-tile] * P^T[m-tile][n]
        #pragma unroll
        for (int ks = 0; ks < 2; ++ks){
            bf16x8 av[4];
            #pragma unroll
            for (int ct = 0; ct < 4; ++ct)
                av[ct] = *reinterpret_cast<const bf16x8*>(
                    vb + (w*64 + ct*16 + r) * NN + m0 + ks*32 + 8*h);
            bf16x8 bv2[4];
            #pragma unroll
            for (int nt = 0; nt < 4; ++nt)
                bv2[nt] = *reinterpret_cast<const bf16x8*>(
                    &ps[(nt*16 + r) * 72 + ks*32 + 8*h]);
            #pragma unroll
            for (int ct = 0; ct < 4; ++ct)
                #pragma unroll
                for (int nt = 0; nt < 4; ++nt)
                    acc[ct][nt] = __builtin_amdgcn_mfma_f32_16x16x32_bf16(
                        av[ct], bv2[nt], acc[ct][nt], 0, 0, 0);
        }
        __syncthreads();
    }

    #pragma unroll
    for (int ct = 0; ct < 4; ++ct)
        #pragma unroll
        for (int nt = 0; nt < 4; ++nt)
            #pragma unroll
            for (int g2 = 0; g2 < 4; ++g2)
                atomicAdd(outacc + (w*64 + ct*16 + 4*h + g2) * NN + n0 + nt*16 + r,
                          acc[ct][nt][g2]);
}

// ---------------- K4: out = gamma*acc + x ----------------
extern "C" __global__ __launch_bounds__(256)
void epilogue(const float* __restrict__ x, const float* __restrict__ gm,
              float* __restrict__ outf)
{
    const float g = gm[0];
    const size_t i = ((size_t)blockIdx.x * 256 + threadIdx.x) * 4;
    float4 a  = *reinterpret_cast<float4*>(outf + i);
    float4 xv = *reinterpret_cast<const float4*>(x + i);
    a.x = fmaf(g, a.x, xv.x);
    a.y = fmaf(g, a.y, xv.y);
    a.z = fmaf(g, a.z, xv.z);
    a.w = fmaf(g, a.w, xv.w);
    *reinterpret_cast<float4*>(outf + i) = a;
}

extern "C" void kernel_launch(void* const* d_in, const int* in_sizes, int n_in,
                              void* d_out, int out_size, void* d_ws, size_t ws_size,
                              hipStream_t stream)
{
    (void)in_sizes; (void)n_in; (void)out_size; (void)ws_size;
    const float* x  = (const float*)d_in[0];
    const float* sf = (const float*)d_in[1];
    const float* Wq = (const float*)d_in[2];
    const float* bq = (const float*)d_in[3];
    const float* Wk = (const float*)d_in[4];
    const float* bk = (const float*)d_in[5];
    const float* Wv = (const float*)d_in[6];
    const float* bv = (const float*)d_in[7];
    const float* gm = (const float*)d_in[8];

    float* outf  = (float*)d_out;                       // [256][9216] f32 (accumulator then final)
    float* attnf = outf + (size_t)256 * 9216;           // [9216][9216] f32

    char* ws = (char*)d_ws;
    u16*   qhb   = (u16*)(ws);                          // [9216][32] bf16 = 589,824 B
    u16*   khb   = (u16*)(ws + 589824);                 // [9216][32] bf16 = 589,824 B
    u16*   vbp   = (u16*)(ws + 1179648);                // [256][9216] bf16 = 4,718,592 B
    float* rsums = (float*)(ws + 5898240);              // [9216] f32 = 36,864 B
    float* pq    = (float*)(ws + 5935104);              // [72] f32
    float* pk    = pq + 72;                             // [72] f32   (end ~5.936 MB)

    zero_ws  <<<dim3(2313), dim3(256), 0, stream>>>(outf, rsums);
    proj_all <<<dim3(360),  dim3(256), 0, stream>>>(x, sf, Wq, bq, Wk, bk, Wv, bv,
                                                    qhb, khb, vbp, pq, pk);
    rowsums_k<<<dim3(1152), dim3(256), 0, stream>>>(qhb, khb, pq, pk, rsums);
    attn_main<<<dim3(1152), dim3(256), 0, stream>>>(qhb, khb, vbp, pq, pk, rsums,
                                                    outf, attnf);
    epilogue <<<dim3(2304), dim3(256), 0, stream>>>(x, gm, outf);
}